// Round 8
// baseline (341.857 us; speedup 1.0000x reference)
//
#include <hip/hip_runtime.h>
#include <hip/hip_bf16.h>
#include <cstddef>

#define HW   50176
#define NPIX 100352
#define IW   224

typedef unsigned short ushort_t;
typedef __attribute__((ext_vector_type(8))) short bf16x8;
typedef __attribute__((ext_vector_type(8))) unsigned short ushort8;
typedef __attribute__((ext_vector_type(4))) float f32x4;
typedef __attribute__((ext_vector_type(2))) _Float16 f16x2;
typedef __attribute__((ext_vector_type(8))) _Float16 f16x8;

__device__ inline ushort_t f2bf(float f) {
    __hip_bfloat16 h = __float2bfloat16(f);
    return __builtin_bit_cast(ushort_t, h);
}
__device__ inline float bf2f(ushort_t u) {
    return __uint_as_float(((unsigned)u) << 16);
}
__device__ inline bf16x8 ldg8(const ushort_t* p) {
    return *reinterpret_cast<const bf16x8*>(p);
}
__device__ inline void b2f8(const ushort_t* p, float* f) {
    ushort8 v = *reinterpret_cast<const ushort8*>(p);
#pragma unroll
    for (int i = 0; i < 8; i++) f[i] = bf2f(v[i]);
}
__device__ inline f16x2 pk16(float a, float b) {
    return __builtin_bit_cast(f16x2, __builtin_amdgcn_cvt_pkrtz(a, b));
}

// async global->LDS DMA, 16 B per lane; lds dest must be wave-uniform.
__device__ inline void dma16(const ushort_t* g, ushort_t* l) {
    __builtin_amdgcn_global_load_lds(
        (const __attribute__((address_space(1))) void*)g,
        (__attribute__((address_space(3))) void*)l, 16, 0, 0);
}

// ---------------------------------------------------------------------------
// merged prep + conv1 kernel
// ---------------------------------------------------------------------------
__device__ void conv1_body(int gid, const float* __restrict__ x,
                           const float* __restrict__ w,
                           const float* __restrict__ bias,
                           ushort_t* __restrict__ out)
{
    int b = gid >= HW;
    int p = gid - b * HW;
    int y = p / IW, xx = p - y * IW;

    float v[27];
#pragma unroll
    for (int ci = 0; ci < 3; ci++) {
        const float* ip = x + ((size_t)(b * 3 + ci)) * HW;
#pragma unroll
        for (int t = 0; t < 9; t++) {
            int dy = t / 3 - 1, dx = t % 3 - 1;
            int yy = y + dy, xc = xx + dx;
            float tv = 0.f;
            if ((unsigned)yy < (unsigned)IW && (unsigned)xc < (unsigned)IW)
                tv = ip[yy * IW + xc];
            v[ci * 9 + t] = tv;
        }
    }
#pragma unroll
    for (int g = 0; g < 8; g++) {
        ushort8 o8;
#pragma unroll
        for (int i = 0; i < 8; i++) {
            int co = g * 8 + i;
            float a = bias[co];
            const float* wp = w + co * 27;
#pragma unroll
            for (int k = 0; k < 27; k++) a = fmaf(v[k], wp[k], a);
            o8[i] = f2bf(fmaxf(a, 0.f));
        }
        *reinterpret_cast<ushort8*>(out + (size_t)gid * 64 + g * 8) = o8;
    }
}

__global__ __launch_bounds__(256) void prep_conv1_k(
    const float* __restrict__ x,     const float* __restrict__ enc_w1,
    const float* __restrict__ enc_b1, ushort_t* __restrict__ E1b,
    const float* __restrict__ in_w,  ushort_t* __restrict__ in_wb,
    const float* __restrict__ out_w, ushort_t* __restrict__ out_wb,
    const float* __restrict__ w1,    ushort_t* __restrict__ w1p,
    const float* __restrict__ w2,    _Float16* __restrict__ w2s,
    const float* __restrict__ ec2,   ushort_t* __restrict__ wc2p,
    const float* __restrict__ s1,    ushort_t* __restrict__ ws1p,
    const float* __restrict__ s2,    ushort_t* __restrict__ ws2)
{
    if (blockIdx.x < 392) {
        conv1_body(blockIdx.x * 256 + threadIdx.x, x, enc_w1, enc_b1, E1b);
        return;
    }
    int idx = (blockIdx.x - 392) * 256 + threadIdx.x;
    if (idx < 12288) { in_wb[idx] = f2bf(in_w[idx]); return; }
    idx -= 12288;
    if (idx < 4096)  { out_wb[idx] = f2bf(out_w[idx]); return; }
    idx -= 4096;
    if (idx < 131072){
        int j = idx >> 6, e = idx & 63;
        int c = j >> 6, jl = j & 63;
        w1p[(size_t)c * 6144 + jl * 72 + e] = f2bf(w1[idx]);
        return;
    }
    idx -= 131072;
    if (idx < 131072){
        int j    = idx & 7;
        int lane = (idx >> 3) & 63;
        int rest = idx >> 9;          // (c*2+p)*4+nt
        int nt   = rest & 3;
        int cp   = rest >> 2;         // c*2+p
        int p    = cp & 1;
        int c    = cp >> 1;
        int quad = lane >> 4;
        int e2   = nt * 16 + (lane & 15);
        int hl   = (j < 4) ? (quad * 4 + j) : (16 + quad * 4 + (j - 4));
        int hidden = c * 64 + p * 32 + hl;
        w2s[idx] = (_Float16)w2[(size_t)e2 * 2048 + hidden];
        return;
    }
    idx -= 131072;
    if (idx < 36864) {
        // coalesced MFMA B-fragment layout for enc conv2:
        // wc2p[(t*8 + nt*2 + ks)*512 + lane*8 + j]
        //   = ec2[co=nt*16+(lane&15)][ci=ks*32+(lane>>4)*8+j][t]
        int j    = idx & 7;
        int lane = (idx >> 3) & 63;
        int rest = idx >> 9;          // t*8 + nt*2 + ks, 0..71
        int ks   = rest & 1;
        int nt   = (rest >> 1) & 3;
        int t    = rest >> 3;
        int co   = nt * 16 + (lane & 15);
        int ci   = ks * 32 + (lane >> 4) * 8 + j;
        wc2p[idx] = f2bf(ec2[((size_t)co * 64 + ci) * 9 + t]);
        return;
    }
    idx -= 36864;
    if (idx < 18432) {
        // coalesced MFMA B-fragment layout for sf1 conv (64->32):
        // ws1p[(t*4 + nt*2 + ks)*512 + lane*8 + j]
        //   = s1[co=nt*16+(lane&15)][ci=ks*32+(lane>>4)*8+j][t]
        int j    = idx & 7;
        int lane = (idx >> 3) & 63;
        int rest = idx >> 9;          // t*4 + nt*2 + ks, 0..35
        int ks   = rest & 1;
        int nt   = (rest >> 1) & 1;
        int t    = rest >> 2;
        int co   = nt * 16 + (lane & 15);
        int ci   = ks * 32 + (lane >> 4) * 8 + j;
        ws1p[idx] = f2bf(s1[((size_t)co * 64 + ci) * 9 + t]);
        return;
    }
    idx -= 18432;
    if (idx < 4608)  {
        int ci = idx % 32;
        int t  = (idx / 32) % 9;
        int co = idx / 288;
        ws2[idx] = (co < 9) ? f2bf(s2[((size_t)co * 32 + ci) * 9 + t]) : (ushort_t)0;
        return;
    }
}

// ---------------------------------------------------------------------------
// FUSED enc-conv2 + transformer front (R5 winner: batch-issued loads, 2,256).
// ---------------------------------------------------------------------------
__global__ __launch_bounds__(256, 2) void enc2xf_k(
    const ushort_t* __restrict__ E1b, const ushort_t* __restrict__ Wc2p,
    const float* __restrict__ enc_b2,
    const ushort_t* __restrict__ Wqkv, const float* __restrict__ Bqkv,
    const ushort_t* __restrict__ Wo, const float* __restrict__ Bo,
    const float* __restrict__ g, const float* __restrict__ be,
    ushort_t* __restrict__ T1b)
{
    __shared__ ushort_t Q[128 * 200];   // 51.2 KB
    __shared__ ushort_t WT[9216];       // 18.4 KB: Tl[128*72]

    int tid = threadIdx.x, wave = tid >> 6, lane = tid & 63;
    int lm = lane & 15, quad = lane >> 4;
    int p0 = blockIdx.x * 64;

    // ---- phase 0: enc conv2 (64->64, 3x3), all-taps-hoisted loads ----
    {
        int lr0 = wave * 32;
        int m[2], py[2], px[2];
#pragma unroll
        for (int mt = 0; mt < 2; mt++) {
            int lr = lr0 + mt * 16 + lm;
            int gp = p0 + (lr & 63);
            m[mt] = (lr >> 6) * HW + gp;
            py[mt] = gp / IW;
            px[mt] = gp - py[mt] * IW;
        }

        f32x4 acc[2][4] = {};
        bf16x8 zz = {};
        bf16x8 af[9][2][2];

        // issue ALL 36 input loads back-to-back: ~36 loads in flight.
#pragma unroll
        for (int t = 0; t < 9; t++) {
            int dy = t / 3 - 1, dx = t % 3 - 1;
#pragma unroll
            for (int mt = 0; mt < 2; mt++) {
                bool ok = (unsigned)(py[mt] + dy) < (unsigned)IW &&
                          (unsigned)(px[mt] + dx) < (unsigned)IW;
                const ushort_t* ip = E1b + (size_t)(m[mt] + dy * IW + dx) * 64 + quad * 8;
#pragma unroll
                for (int ks = 0; ks < 2; ks++)
                    af[t][mt][ks] = ok ? ldg8(ip + ks * 32) : zz;
            }
        }

        // weight fragments stream from L2 under the MFMA loop.
#pragma unroll
        for (int t = 0; t < 9; t++) {
#pragma unroll
            for (int nt = 0; nt < 4; nt++)
#pragma unroll
                for (int ks = 0; ks < 2; ks++) {
                    bf16x8 bfv = ldg8(Wc2p + (size_t)(t * 8 + nt * 2 + ks) * 512 + lane * 8);
#pragma unroll
                    for (int mt = 0; mt < 2; mt++)
                        acc[mt][nt] = __builtin_amdgcn_mfma_f32_16x16x32_bf16(
                            af[t][mt][ks], bfv, acc[mt][nt], 0, 0, 0);
                }
        }

#pragma unroll
        for (int nt = 0; nt < 4; nt++) {
            float bv = enc_b2[nt * 16 + lm];
#pragma unroll
            for (int mt = 0; mt < 2; mt++)
#pragma unroll
                for (int r = 0; r < 4; r++) {
                    int lr = lr0 + mt * 16 + quad * 4 + r;
                    WT[lr * 72 + nt * 16 + lm] =
                        f2bf(fmaxf(acc[mt][nt][r] + bv, 0.f));
                }
        }
    }

    // hoist Wqkv fragments (mt-invariant) BEFORE the barrier: the conv
    // epilogue + barrier drain covers their L2 latency.
    bf16x8 wq[12][2];
#pragma unroll
    for (int nt = 0; nt < 12; nt++)
#pragma unroll
        for (int ks = 0; ks < 2; ks++)
            wq[nt][ks] = ldg8(Wqkv + (size_t)(nt * 16 + lm) * 64 + ks * 32 + quad * 8);

    __syncthreads();

    // ---- phase A: qkv projection (input from Tl) into Q ----
#pragma unroll
    for (int mt = 0; mt < 2; mt++) {
        int lA = mt * 64 + wave * 16;
        bf16x8 a[2];
#pragma unroll
        for (int ks = 0; ks < 2; ks++)
            a[ks] = *reinterpret_cast<const bf16x8*>(
                &WT[(lA + lm) * 72 + ks * 32 + quad * 8]);
        f32x4 acc[12] = {};
#pragma unroll
        for (int nt = 0; nt < 12; nt++)
#pragma unroll
            for (int ks = 0; ks < 2; ks++)
                acc[nt] = __builtin_amdgcn_mfma_f32_16x16x32_bf16(
                    a[ks], wq[nt][ks], acc[nt], 0, 0, 0);
        int lrow = lA + quad * 4;
#pragma unroll
        for (int nt = 0; nt < 12; nt++) {
            float bb = Bqkv[nt * 16 + lm];
#pragma unroll
            for (int r = 0; r < 4; r++)
                Q[(lrow + r) * 200 + nt * 16 + lm] = f2bf(acc[nt][r] + bb);
        }
    }
    __syncthreads();

    // ---- phase B: attention (per pixel x head, S=2) ----
    {
        int px = tid >> 2, h = tid & 3;
        ushort_t* r0 = &Q[px * 200 + h * 16];
        ushort_t* r1 = &Q[(64 + px) * 200 + h * 16];

        float q0[16], k0[16], v0[16], q1[16], k1[16], v1[16];
        b2f8(r0,       q0); b2f8(r0 + 8,   q0 + 8);
        b2f8(r0 + 64,  k0); b2f8(r0 + 72,  k0 + 8);
        b2f8(r0 + 128, v0); b2f8(r0 + 136, v0 + 8);
        b2f8(r1,       q1); b2f8(r1 + 8,   q1 + 8);
        b2f8(r1 + 64,  k1); b2f8(r1 + 72,  k1 + 8);
        b2f8(r1 + 128, v1); b2f8(r1 + 136, v1 + 8);

        float s00 = 0, s01 = 0, s10 = 0, s11 = 0;
#pragma unroll
        for (int d = 0; d < 16; d++) {
            s00 += q0[d] * k0[d]; s01 += q0[d] * k1[d];
            s10 += q1[d] * k0[d]; s11 += q1[d] * k1[d];
        }
        s00 *= 0.25f; s01 *= 0.25f; s10 *= 0.25f; s11 *= 0.25f;

        float m0 = fmaxf(s00, s01);
        float e00 = __expf(s00 - m0), e01 = __expf(s01 - m0);
        float i0 = 1.f / (e00 + e01);
        float p00 = e00 * i0, p01 = e01 * i0;

        float m1 = fmaxf(s10, s11);
        float e10 = __expf(s10 - m1), e11 = __expf(s11 - m1);
        float i1 = 1.f / (e10 + e11);
        float p10 = e10 * i1, p11 = e11 * i1;

#pragma unroll
        for (int c = 0; c < 2; c++) {
            ushort8 a0v, a1v;
#pragma unroll
            for (int i = 0; i < 8; i++) {
                int d = c * 8 + i;
                a0v[i] = f2bf(p00 * v0[d] + p01 * v1[d]);
                a1v[i] = f2bf(p10 * v0[d] + p11 * v1[d]);
            }
            *reinterpret_cast<ushort8*>(r0 + c * 8) = a0v;
            *reinterpret_cast<ushort8*>(r1 + c * 8) = a1v;
        }
    }

    // hoist Wo fragments (mt-invariant) before the barrier.
    bf16x8 wo[4][2];
#pragma unroll
    for (int nt = 0; nt < 4; nt++)
#pragma unroll
        for (int ks = 0; ks < 2; ks++)
            wo[nt][ks] = ldg8(Wo + (size_t)(nt * 16 + lm) * 64 + ks * 32 + quad * 8);

    __syncthreads();

    // ---- phase C: out-proj + residual(Tl) + LN1 -> t1 (global) ----
#pragma unroll
    for (int mt = 0; mt < 2; mt++) {
        int lA = mt * 64 + wave * 16;
        size_t gbase = (size_t)((mt == 0 ? p0 : HW + p0) + wave * 16);
        bf16x8 a[2];
#pragma unroll
        for (int ks = 0; ks < 2; ks++)
            a[ks] = *reinterpret_cast<const bf16x8*>(
                &Q[(lA + lm) * 200 + ks * 32 + quad * 8]);
        f32x4 acc[4] = {};
#pragma unroll
        for (int nt = 0; nt < 4; nt++)
#pragma unroll
            for (int ks = 0; ks < 2; ks++)
                acc[nt] = __builtin_amdgcn_mfma_f32_16x16x32_bf16(
                    a[ks], wo[nt][ks], acc[nt], 0, 0, 0);

        float bv[4], gv[4], bev[4];
#pragma unroll
        for (int nt = 0; nt < 4; nt++) {
            bv[nt]  = Bo[nt * 16 + lm];
            gv[nt]  = g[nt * 16 + lm];
            bev[nt] = be[nt * 16 + lm];
        }
#pragma unroll
        for (int r = 0; r < 4; r++) {
            int lr = lA + quad * 4 + r;
            size_t row = gbase + quad * 4 + r;
            float v[4]; float s = 0.f;
#pragma unroll
            for (int nt = 0; nt < 4; nt++) {
                v[nt] = acc[nt][r] + bv[nt] + bf2f(WT[lr * 72 + nt * 16 + lm]);
                s += v[nt];
            }
#pragma unroll
            for (int o = 8; o; o >>= 1) s += __shfl_xor(s, o, 64);
            float mu = s * 0.015625f;
            float q = 0.f;
#pragma unroll
            for (int nt = 0; nt < 4; nt++) { v[nt] -= mu; q += v[nt] * v[nt]; }
#pragma unroll
            for (int o = 8; o; o >>= 1) q += __shfl_xor(q, o, 64);
            float rstd = rsqrtf(q * 0.015625f + 1e-5f);
#pragma unroll
            for (int nt = 0; nt < 4; nt++)
                T1b[row * 64 + nt * 16 + lm] = f2bf(gv[nt] * v[nt] * rstd + bev[nt]);
        }
    }
}

// ---------------------------------------------------------------------------
// sf1 conv (64->32) v2: no LDS, zero barriers, batch-issued loads.
// ---------------------------------------------------------------------------
__global__ __launch_bounds__(256, 2) void neconv2_k(
    const ushort_t* __restrict__ In, const ushort_t* __restrict__ Wp,
    const float* __restrict__ bias, ushort_t* __restrict__ Ob)
{
    int tid = threadIdx.x, wave = tid >> 6, lane = tid & 63;
    int lm = lane & 15, quad = lane >> 4;
    int m0 = blockIdx.x * 128 + wave * 32;

    int m[2], py[2], px[2];
#pragma unroll
    for (int mt = 0; mt < 2; mt++) {
        int mm = m0 + mt * 16 + lm;
        m[mt] = mm;
        int p = mm - (mm >= HW ? HW : 0);
        py[mt] = p / IW;
        px[mt] = p - py[mt] * IW;
    }

    f32x4 acc[2][2] = {};
    bf16x8 zz = {};
    bf16x8 af[9][2][2];

    // issue ALL 36 input loads back-to-back for MLP.
#pragma unroll
    for (int t = 0; t < 9; t++) {
        int dy = t / 3 - 1, dx = t % 3 - 1;
#pragma unroll
        for (int mt = 0; mt < 2; mt++) {
            bool ok = (unsigned)(py[mt] + dy) < (unsigned)IW &&
                      (unsigned)(px[mt] + dx) < (unsigned)IW;
            const ushort_t* ip = In + (size_t)(m[mt] + dy * IW + dx) * 64 + quad * 8;
#pragma unroll
            for (int ks = 0; ks < 2; ks++)
                af[t][mt][ks] = ok ? ldg8(ip + ks * 32) : zz;
        }
    }

    // weight fragments stream from L2 under the MFMA loop.
#pragma unroll
    for (int t = 0; t < 9; t++) {
#pragma unroll
        for (int nt = 0; nt < 2; nt++)
#pragma unroll
            for (int ks = 0; ks < 2; ks++) {
                bf16x8 bfv = ldg8(Wp + (size_t)(t * 4 + nt * 2 + ks) * 512 + lane * 8);
#pragma unroll
                for (int mt = 0; mt < 2; mt++)
                    acc[mt][nt] = __builtin_amdgcn_mfma_f32_16x16x32_bf16(
                        af[t][mt][ks], bfv, acc[mt][nt], 0, 0, 0);
            }
    }

#pragma unroll
    for (int nt = 0; nt < 2; nt++) {
        int col = nt * 16 + lm;
        float bv = bias[col];
#pragma unroll
        for (int mt = 0; mt < 2; mt++)
#pragma unroll
            for (int r = 0; r < 4; r++) {
                int row = m0 + mt * 16 + quad * 4 + r;
                Ob[(size_t)row * 32 + col] = f2bf(acc[mt][nt][r] + bv);
            }
    }
}

// ---------------------------------------------------------------------------
// FFN v13: hidden-split wave pairs. Wave w (pid=w&3, ph=w>>2) computes
// rows [pid*64,+64) (mt=4) for hidden-half ph only -> 10 LDS reads/chunk
// instead of 20 per wave (the redundant shared-weight reads halve), at
// UNCHANGED block shape / DMA / counted-vmcnt pipeline (ffn9-proven).
// Partner partial sums reduced via LDS (reusing dead weight buffers).
// ---------------------------------------------------------------------------
__global__ __launch_bounds__(512, 2) void ffn13_k(
    const ushort_t* __restrict__ T1b,
    const ushort_t* __restrict__ W1p, const float* __restrict__ B1,
    const _Float16* __restrict__ W2s, const float* __restrict__ B2,
    const float* __restrict__ g, const float* __restrict__ be,
    ushort_t* __restrict__ OutTb)
{
    __shared__ __align__(16) unsigned char SMEM[69632];
    ushort_t* W1base = (ushort_t*)SMEM;            // [3][6144] ushort
    ushort_t* W2base = (ushort_t*)(SMEM + 36864);  // [3][4096] ushort
    float*    B1l    = (float*)(SMEM + 61440);     // 2048 f32
    float*    red    = (float*)SMEM;               // 16384 f32 scratch (reuse)

    int tid = threadIdx.x, wave = tid >> 6, lane = tid & 63;
    int lm = lane & 15, quad = lane >> 4;
    int pid = wave & 3;          // row-group (pair) id
    int ph  = wave >> 2;         // hidden half handled by this wave
    int rowbase = blockIdx.x * 256 + pid * 64;

    // stage B1 into LDS (512 threads x float4)
    *reinterpret_cast<float4*>(&B1l[tid * 4]) =
        *reinterpret_cast<const float4*>(B1 + tid * 4);

    bf16x8 Bt[4][2];
#pragma unroll
    for (int mt = 0; mt < 4; mt++)
#pragma unroll
        for (int ks = 0; ks < 2; ks++)
            Bt[mt][ks] = ldg8(T1b + (size_t)(rowbase + mt * 16 + lm) * 64 + ks * 32 + quad * 8);

    // full drain + barrier BEFORE any DMA: B1l visible, vmcnt clean.
    __syncthreads();

    auto dma_chunk = [&](int c, int pb) {
        const ushort_t* g1 = W1p + (size_t)c * 6144;
        const ushort_t* g2 = (const ushort_t*)(W2s + (size_t)c * 4096);
#pragma unroll
        for (int i = 0; i < 3; i++) {
            int idx = i * 8 + wave;
            if (idx < 12)
                dma16(g1 + idx * 512 + lane * 8, W1base + pb * 6144 + idx * 512);
            else if (idx < 20)
                dma16(g2 + (idx - 12) * 512 + lane * 8,
                      W2base + pb * 4096 + (idx - 12) * 512);
        }
    };
    // per-wave loads per chunk: waves 0-3 issue 3, waves 4-7 issue 2.

    dma_chunk(0, 0);
    dma_chunk(1, 1);

    f32x4 acc[4][4] = {};

    for (int c = 0; c < 32; c++) {
        int pb = c % 3;

        // counted wait: retire own chunk-c loads, leave chunk-(c+1) in flight.
        if (c < 31) {
            if (wave < 4) asm volatile("s_waitcnt vmcnt(3)" ::: "memory");
            else          asm volatile("s_waitcnt vmcnt(2)" ::: "memory");
        } else {
            asm volatile("s_waitcnt vmcnt(0)" ::: "memory");
        }
        __builtin_amdgcn_s_barrier();
        asm volatile("" ::: "memory");   // fence: no ds_read hoists above barrier

        // depth-2 prefetch: buffer (c+2)%3 == (c-1)%3, fully consumed already.
        if (c + 2 < 32) dma_chunk(c + 2, (c + 2) % 3);

        const ushort_t* w1l = W1base + pb * 6144;
        const ushort_t* w2l = W2base + pb * 4096;

        // this wave's hidden half only: ul = ph*2 + s.
        bf16x8 w1r[2][2];
        f16x8  w2r[4];
        float4 b1r[2];
#pragma unroll
        for (int s = 0; s < 2; s++) {
            int ul = ph * 2 + s;
#pragma unroll
            for (int ks = 0; ks < 2; ks++)
                w1r[s][ks] = *reinterpret_cast<const bf16x8*>(
                    &w1l[(ul * 16 + lm) * 72 + ks * 32 + quad * 8]);
            b1r[s] = *reinterpret_cast<const float4*>(
                &B1l[(c * 4 + ul) * 16 + quad * 4]);
        }
#pragma unroll
        for (int nt = 0; nt < 4; nt++)
            w2r[nt] = *reinterpret_cast<const f16x8*>(
                &w2l[((ph * 4 + nt) * 64 + lane) * 8]);

        f32x4 h[2][4];
#pragma unroll
        for (int s = 0; s < 2; s++) {
            f32x4 binit = {b1r[s].x, b1r[s].y, b1r[s].z, b1r[s].w};
#pragma unroll
            for (int mt = 0; mt < 4; mt++) h[s][mt] = binit;
        }

        __builtin_amdgcn_s_setprio(1);
#pragma unroll
        for (int s = 0; s < 2; s++)
#pragma unroll
            for (int ks = 0; ks < 2; ks++)
#pragma unroll
                for (int mt = 0; mt < 4; mt++)
                    h[s][mt] = __builtin_amdgcn_mfma_f32_16x16x32_bf16(
                        w1r[s][ks], Bt[mt][ks], h[s][mt], 0, 0, 0);

        f16x8 aH[4];
#pragma unroll
        for (int mt = 0; mt < 4; mt++) {
            f16x2 t0 = pk16(fmaxf(h[0][mt][0], 0.f), fmaxf(h[0][mt][1], 0.f));
            f16x2 t1 = pk16(fmaxf(h[0][mt][2], 0.f), fmaxf(h[0][mt][3], 0.f));
            f16x2 t2 = pk16(fmaxf(h[1][mt][0], 0.f), fmaxf(h[1][mt][1], 0.f));
            f16x2 t3 = pk16(fmaxf(h[1][mt][2], 0.f), fmaxf(h[1][mt][3], 0.f));
            f16x8 a;
            a[0] = t0[0]; a[1] = t0[1]; a[2] = t1[0]; a[3] = t1[1];
            a[4] = t2[0]; a[5] = t2[1]; a[6] = t3[0]; a[7] = t3[1];
            aH[mt] = a;
        }

#pragma unroll
        for (int nt = 0; nt < 4; nt++)
#pragma unroll
            for (int mt = 0; mt < 4; mt++)
                acc[mt][nt] = __builtin_amdgcn_mfma_f32_16x16x32_f16(
                    aH[mt], w2r[nt], acc[mt][nt], 0, 0, 0);
        __builtin_amdgcn_s_setprio(0);
    }

    // ---- cross-wave (hidden-half) reduction via LDS (weights now dead) ----
    __syncthreads();
    if (wave >= 4) {
        float* dst = red + pid * 4096;
#pragma unroll
        for (int mt = 0; mt < 4; mt++)
#pragma unroll
            for (int nt = 0; nt < 4; nt++)
                *reinterpret_cast<f32x4*>(dst + (mt * 4 + nt) * 256 + lane * 4) =
                    acc[mt][nt];
    }
    __syncthreads();
    if (wave < 4) {
        const float* src = red + pid * 4096;
#pragma unroll
        for (int mt = 0; mt < 4; mt++)
#pragma unroll
            for (int nt = 0; nt < 4; nt++)
                acc[mt][nt] += *reinterpret_cast<const f32x4*>(
                    src + (mt * 4 + nt) * 256 + lane * 4);

        float b2v[4], gv[4], bev[4];
#pragma unroll
        for (int nt = 0; nt < 4; nt++) {
            b2v[nt] = B2[nt * 16 + lm];
            gv[nt]  = g[nt * 16 + lm];
            bev[nt] = be[nt * 16 + lm];
        }
#pragma unroll
        for (int mt = 0; mt < 4; mt++)
#pragma unroll
            for (int r = 0; r < 4; r++) {
                int row = rowbase + mt * 16 + quad * 4 + r;
                float v[4]; float s = 0.f;
#pragma unroll
                for (int nt = 0; nt < 4; nt++) {
                    v[nt] = acc[mt][nt][r] + b2v[nt] +
                            bf2f(T1b[(size_t)row * 64 + nt * 16 + lm]);
                    s += v[nt];
                }
#pragma unroll
                for (int o = 8; o; o >>= 1) s += __shfl_xor(s, o, 64);
                float mu = s * 0.015625f;
                float q = 0.f;
#pragma unroll
                for (int nt = 0; nt < 4; nt++) { v[nt] -= mu; q += v[nt] * v[nt]; }
#pragma unroll
                for (int o = 8; o; o >>= 1) q += __shfl_xor(q, o, 64);
                float rstd = rsqrtf(q * 0.015625f + 1e-5f);
#pragma unroll
                for (int nt = 0; nt < 4; nt++)
                    OutTb[(size_t)row * 64 + nt * 16 + lm] =
                        f2bf(gv[nt] * v[nt] * rstd + bev[nt]);
            }
    }
}

// ---------------------------------------------------------------------------
// sf2 conv (32->9, MFMA) fused with KPN dynamic filtering (R6 batch-issue).
// ---------------------------------------------------------------------------
__global__ __launch_bounds__(256) void sf2kpn_k(
    const ushort_t* __restrict__ In,
    const ushort_t* __restrict__ Wsw,
    const float* __restrict__ bias,
    const float* __restrict__ x,
    float* __restrict__ fused)
{
    __shared__ float Fl[128 * 12];
    int tid = threadIdx.x, wave = tid >> 6, lane = tid & 63;
    int lm = lane & 15, quad = lane >> 4;
    int m0 = blockIdx.x * 128 + wave * 32;

    int m[2], py[2], px[2];
#pragma unroll
    for (int mt = 0; mt < 2; mt++) {
        int mm = m0 + mt * 16 + lm;
        m[mt] = mm;
        int p = mm - (mm >= HW ? HW : 0);
        py[mt] = p / IW;
        px[mt] = p - py[mt] * IW;
    }

    f32x4 acc[2] = {};
    bf16x8 zz = {};
    bf16x8 af[9][2];
    bf16x8 wv[9];

    // batch-issue all input + weight loads for MLP.
#pragma unroll
    for (int t = 0; t < 9; t++) {
        int dy = t / 3 - 1, dx = t % 3 - 1;
#pragma unroll
        for (int mt = 0; mt < 2; mt++) {
            bool ok = (unsigned)(py[mt] + dy) < (unsigned)IW &&
                      (unsigned)(px[mt] + dx) < (unsigned)IW;
            af[t][mt] = ok ? ldg8(In + (size_t)(m[mt] + dy * IW + dx) * 32 + quad * 8) : zz;
        }
    }
#pragma unroll
    for (int t = 0; t < 9; t++)
        wv[t] = ldg8(Wsw + ((size_t)lm * 9 + t) * 32 + quad * 8);

#pragma unroll
    for (int t = 0; t < 9; t++)
#pragma unroll
        for (int mt = 0; mt < 2; mt++)
            acc[mt] = __builtin_amdgcn_mfma_f32_16x16x32_bf16(af[t][mt], wv[t], acc[mt], 0, 0, 0);

    if (lm < 9) {
        float bv = bias[lm];
#pragma unroll
        for (int mt = 0; mt < 2; mt++)
#pragma unroll
            for (int r = 0; r < 4; r++) {
                int lrow = wave * 32 + mt * 16 + quad * 4 + r;
                Fl[lrow * 12 + lm] = acc[mt][r] + bv;
            }
    }
    __syncthreads();

    if (tid < 128) {
        int gid = blockIdx.x * 128 + tid;
        int b = gid >= HW;
        int p = gid - b * HW;
        int y = p / IW, xx = p - y * IW;
        const float* fp = &Fl[tid * 12];
        const float* xp = x + (size_t)b * 3 * HW;
        float a = 0.f;
#pragma unroll
        for (int u = 0; u < 3; u++) {
            int yy = y + u - 1;
            if ((unsigned)yy >= (unsigned)IW) continue;
#pragma unroll
            for (int v = 0; v < 3; v++) {
                int xc = xx + v - 1;
                if ((unsigned)xc >= (unsigned)IW) continue;
                int o = yy * IW + xc;
                float s = xp[o] + xp[HW + o] + xp[2 * HW + o];
                a += fp[u * 3 + v] * s;
            }
        }
        fused[gid] = a;
    }
}

// ---------------------------------------------------------------------------
// decoder split: dec1 conv1 1->64 + relu -> f16 hidden map (channels-last),
// dec2 conv2 64->1 + sigmoid with f16x8 vector loads.
// ---------------------------------------------------------------------------
__global__ __launch_bounds__(256) void dec1_k(
    const float* __restrict__ fused,
    const float* __restrict__ w1, const float* __restrict__ b1,
    _Float16* __restrict__ Hb)
{
    int gid = blockIdx.x * 256 + threadIdx.x;
    int b = gid >= HW;
    int p = gid - b * HW;
    int y = p / IW, xx = p - y * IW;
    const float* ip = fused + (size_t)b * HW;

    float F[9];
#pragma unroll
    for (int s = 0; s < 9; s++) {
        int yy = y + s / 3 - 1, xc = xx + s % 3 - 1;
        float t = 0.f;
        if ((unsigned)yy < (unsigned)IW && (unsigned)xc < (unsigned)IW)
            t = ip[yy * IW + xc];
        F[s] = t;
    }
    _Float16* op = Hb + (size_t)gid * 64;
#pragma unroll
    for (int g = 0; g < 8; g++) {
        f16x8 o;
#pragma unroll
        for (int i = 0; i < 8; i++) {
            int c = g * 8 + i;
            float h = b1[c];
            const float* wp = w1 + c * 9;
#pragma unroll
            for (int s = 0; s < 9; s++) h = fmaf(F[s], wp[s], h);
            o[i] = (_Float16)fmaxf(h, 0.f);
        }
        *reinterpret_cast<f16x8*>(op + g * 8) = o;
    }
}

__global__ __launch_bounds__(256) void dec2_k(
    const _Float16* __restrict__ Hb,
    const float* __restrict__ w2, const float* __restrict__ b2,
    float* __restrict__ out)
{
    int gid = blockIdx.x * 256 + threadIdx.x;
    int b = gid >= HW;
    int p = gid - b * HW;
    int y = p / IW, xx = p - y * IW;
    (void)b;

    float acc = b2[0];
#pragma unroll
    for (int n = 0; n < 9; n++) {
        int dy = n / 3 - 1, dx = n % 3 - 1;
        int yy = y + dy, xc = xx + dx;
        if ((unsigned)yy >= (unsigned)IW || (unsigned)xc >= (unsigned)IW) continue;
        const _Float16* hp = Hb + (size_t)(gid + dy * IW + dx) * 64;
#pragma unroll
        for (int g = 0; g < 8; g++) {
            f16x8 hv = *reinterpret_cast<const f16x8*>(hp + g * 8);
#pragma unroll
            for (int i = 0; i < 8; i++)
                acc = fmaf((float)hv[i], w2[(g * 8 + i) * 9 + n], acc);
        }
    }
    out[gid] = 1.f / (1.f + __expf(-acc));
}

// ---------------------------------------------------------------------------
extern "C" void kernel_launch(void* const* d_in, const int* in_sizes, int n_in,
                              void* d_out, int out_size, void* d_ws, size_t ws_size,
                              hipStream_t stream)
{
    const float* x      = (const float*)d_in[0];
    const float* enc_w1 = (const float*)d_in[1];
    const float* enc_b1 = (const float*)d_in[2];
    const float* enc_w2 = (const float*)d_in[3];
    const float* enc_b2 = (const float*)d_in[4];
    const float* in_w   = (const float*)d_in[5];
    const float* in_b   = (const float*)d_in[6];
    const float* out_w  = (const float*)d_in[7];
    const float* out_b  = (const float*)d_in[8];
    const float* ln1_g  = (const float*)d_in[9];
    const float* ln1_b  = (const float*)d_in[10];
    const float* ffn_w1 = (const float*)d_in[11];
    const float* ffn_b1 = (const float*)d_in[12];
    const float* ffn_w2 = (const float*)d_in[13];
    const float* ffn_b2 = (const float*)d_in[14];
    const float* ln2_g  = (const float*)d_in[15];
    const float* ln2_b  = (const float*)d_in[16];
    const float* sf_w1  = (const float*)d_in[17];
    const float* sf_b1  = (const float*)d_in[18];
    const float* sf_w2  = (const float*)d_in[19];
    const float* sf_b2  = (const float*)d_in[20];
    const float* dec_w1 = (const float*)d_in[21];
    const float* dec_b1 = (const float*)d_in[22];
    const float* dec_w2 = (const float*)d_in[23];
    const float* dec_b2 = (const float*)d_in[24];

    float* ws = (float*)d_ws;
    const size_t SZ = (size_t)NPIX * 64;

    ushort_t* E1b  = (ushort_t*)(ws + 5 * SZ);             // conv1 out / t2 bf16
    ushort_t* Tb   = (ushort_t*)(ws + 11 * SZ / 2);        // t1 bf16
    ushort_t* wu   = (ushort_t*)(ws + 6 * SZ);             // weights
    ushort_t* in_wb  = wu;                                 // 12288
    ushort_t* out_wb = wu + 12288;                         // 4096
    ushort_t* w1p    = wu + 16384;                         // 196608 (padded chunks)
    _Float16* w2s    = (_Float16*)(wu + 212992);           // 131072 halves
    ushort_t* wc2p   = wu + 344064;                        // 36864 (coalesced frags)
    ushort_t* ws1p   = wu + 385536;                        // 18432 (coalesced frags)
    ushort_t* ws2    = wu + 408576;                        // 4608
    // late-stage scratch:
    float*    base3 = ws + 3 * SZ;
    ushort_t* s1b   = (ushort_t*)base3;                    // NPIX*32 bf16
    float*    fused = base3 + SZ / 2;                      // NPIX
    _Float16* Hb    = (_Float16*)(ws + 4 * SZ);            // NPIX*64 f16 hidden

    // ---- merged weight prep + conv1 ----
    prep_conv1_k<<<1714, 256, 0, stream>>>(
        x, enc_w1, enc_b1, E1b,
        in_w, in_wb, out_w, out_wb, ffn_w1, w1p,
        ffn_w2, w2s, enc_w2, wc2p, sf_w1, ws1p, sf_w2, ws2);

    // ---- fused enc-conv2 + transformer front -> t1 (Tb) ----
    enc2xf_k<<<784, 256, 0, stream>>>(E1b, wc2p, enc_b2,
                                      in_wb, in_b, out_wb, out_b,
                                      ln1_g, ln1_b, Tb);
    // ---- FFN (+res+LN2) -> t2 (E1b, dead after enc2xf) ----
    ffn13_k<<<392, 512, 0, stream>>>(Tb, w1p, ffn_b1, w2s, ffn_b2, ln2_g, ln2_b, E1b);
    // ---- filter prediction (sf1, barrier-free v2) ----
    neconv2_k<<<784, 256, 0, stream>>>(E1b, ws1p, sf_b1, s1b);
    // ---- sf2 conv + KPN fused ----
    sf2kpn_k<<<784, 256, 0, stream>>>(s1b, ws2, sf_b2, x, fused);
    // ---- decoder: conv1 -> f16 hidden map, then conv2+sigmoid ----
    dec1_k<<<392, 256, 0, stream>>>(fused, dec_w1, dec_b1, Hb);
    dec2_k<<<392, 256, 0, stream>>>(Hb, dec_w2, dec_b2, (float*)d_out);
}

// Round 10
// 295.660 us; speedup vs baseline: 1.1563x; 1.1563x over previous
//
#include <hip/hip_runtime.h>
#include <hip/hip_bf16.h>
#include <cstddef>

#define HW   50176
#define NPIX 100352
#define IW   224

typedef unsigned short ushort_t;
typedef __attribute__((ext_vector_type(8))) short bf16x8;
typedef __attribute__((ext_vector_type(8))) unsigned short ushort8;
typedef __attribute__((ext_vector_type(4))) float f32x4;
typedef __attribute__((ext_vector_type(2))) _Float16 f16x2;
typedef __attribute__((ext_vector_type(8))) _Float16 f16x8;

__device__ inline ushort_t f2bf(float f) {
    __hip_bfloat16 h = __float2bfloat16(f);
    return __builtin_bit_cast(ushort_t, h);
}
__device__ inline float bf2f(ushort_t u) {
    return __uint_as_float(((unsigned)u) << 16);
}
__device__ inline bf16x8 ldg8(const ushort_t* p) {
    return *reinterpret_cast<const bf16x8*>(p);
}
__device__ inline void b2f8(const ushort_t* p, float* f) {
    ushort8 v = *reinterpret_cast<const ushort8*>(p);
#pragma unroll
    for (int i = 0; i < 8; i++) f[i] = bf2f(v[i]);
}
__device__ inline f16x2 pk16(float a, float b) {
    return __builtin_bit_cast(f16x2, __builtin_amdgcn_cvt_pkrtz(a, b));
}

// async global->LDS DMA, 16 B per lane; lds dest must be wave-uniform.
__device__ inline void dma16(const ushort_t* g, ushort_t* l) {
    __builtin_amdgcn_global_load_lds(
        (const __attribute__((address_space(1))) void*)g,
        (__attribute__((address_space(3))) void*)l, 16, 0, 0);
}

// ---------------------------------------------------------------------------
// merged prep + conv1 kernel
// ---------------------------------------------------------------------------
__device__ void conv1_body(int gid, const float* __restrict__ x,
                           const float* __restrict__ w,
                           const float* __restrict__ bias,
                           ushort_t* __restrict__ out)
{
    int b = gid >= HW;
    int p = gid - b * HW;
    int y = p / IW, xx = p - y * IW;

    float v[27];
#pragma unroll
    for (int ci = 0; ci < 3; ci++) {
        const float* ip = x + ((size_t)(b * 3 + ci)) * HW;
#pragma unroll
        for (int t = 0; t < 9; t++) {
            int dy = t / 3 - 1, dx = t % 3 - 1;
            int yy = y + dy, xc = xx + dx;
            float tv = 0.f;
            if ((unsigned)yy < (unsigned)IW && (unsigned)xc < (unsigned)IW)
                tv = ip[yy * IW + xc];
            v[ci * 9 + t] = tv;
        }
    }
#pragma unroll
    for (int g = 0; g < 8; g++) {
        ushort8 o8;
#pragma unroll
        for (int i = 0; i < 8; i++) {
            int co = g * 8 + i;
            float a = bias[co];
            const float* wp = w + co * 27;
#pragma unroll
            for (int k = 0; k < 27; k++) a = fmaf(v[k], wp[k], a);
            o8[i] = f2bf(fmaxf(a, 0.f));
        }
        *reinterpret_cast<ushort8*>(out + (size_t)gid * 64 + g * 8) = o8;
    }
}

__global__ __launch_bounds__(256) void prep_conv1_k(
    const float* __restrict__ x,     const float* __restrict__ enc_w1,
    const float* __restrict__ enc_b1, ushort_t* __restrict__ E1b,
    const float* __restrict__ in_w,  ushort_t* __restrict__ in_wb,
    const float* __restrict__ out_w, ushort_t* __restrict__ out_wb,
    const float* __restrict__ w1,    ushort_t* __restrict__ w1p,
    const float* __restrict__ w2,    _Float16* __restrict__ w2s,
    const float* __restrict__ ec2,   ushort_t* __restrict__ wc2p,
    const float* __restrict__ s1,    ushort_t* __restrict__ ws1p,
    const float* __restrict__ s2,    ushort_t* __restrict__ ws2)
{
    if (blockIdx.x < 392) {
        conv1_body(blockIdx.x * 256 + threadIdx.x, x, enc_w1, enc_b1, E1b);
        return;
    }
    int idx = (blockIdx.x - 392) * 256 + threadIdx.x;
    if (idx < 12288) { in_wb[idx] = f2bf(in_w[idx]); return; }
    idx -= 12288;
    if (idx < 4096)  { out_wb[idx] = f2bf(out_w[idx]); return; }
    idx -= 4096;
    if (idx < 131072){
        int j = idx >> 6, e = idx & 63;
        int c = j >> 6, jl = j & 63;
        w1p[(size_t)c * 6144 + jl * 72 + e] = f2bf(w1[idx]);
        return;
    }
    idx -= 131072;
    if (idx < 131072){
        int j    = idx & 7;
        int lane = (idx >> 3) & 63;
        int rest = idx >> 9;          // (c*2+p)*4+nt
        int nt   = rest & 3;
        int cp   = rest >> 2;         // c*2+p
        int p    = cp & 1;
        int c    = cp >> 1;
        int quad = lane >> 4;
        int e2   = nt * 16 + (lane & 15);
        int hl   = (j < 4) ? (quad * 4 + j) : (16 + quad * 4 + (j - 4));
        int hidden = c * 64 + p * 32 + hl;
        w2s[idx] = (_Float16)w2[(size_t)e2 * 2048 + hidden];
        return;
    }
    idx -= 131072;
    if (idx < 36864) {
        // coalesced MFMA B-fragment layout for enc conv2:
        // wc2p[(t*8 + nt*2 + ks)*512 + lane*8 + j]
        //   = ec2[co=nt*16+(lane&15)][ci=ks*32+(lane>>4)*8+j][t]
        int j    = idx & 7;
        int lane = (idx >> 3) & 63;
        int rest = idx >> 9;          // t*8 + nt*2 + ks, 0..71
        int ks   = rest & 1;
        int nt   = (rest >> 1) & 3;
        int t    = rest >> 3;
        int co   = nt * 16 + (lane & 15);
        int ci   = ks * 32 + (lane >> 4) * 8 + j;
        wc2p[idx] = f2bf(ec2[((size_t)co * 64 + ci) * 9 + t]);
        return;
    }
    idx -= 36864;
    if (idx < 18432) {
        // coalesced MFMA B-fragment layout for sf1 conv (64->32):
        // ws1p[(t*4 + nt*2 + ks)*512 + lane*8 + j]
        //   = s1[co=nt*16+(lane&15)][ci=ks*32+(lane>>4)*8+j][t]
        int j    = idx & 7;
        int lane = (idx >> 3) & 63;
        int rest = idx >> 9;          // t*4 + nt*2 + ks, 0..35
        int ks   = rest & 1;
        int nt   = (rest >> 1) & 1;
        int t    = rest >> 2;
        int co   = nt * 16 + (lane & 15);
        int ci   = ks * 32 + (lane >> 4) * 8 + j;
        ws1p[idx] = f2bf(s1[((size_t)co * 64 + ci) * 9 + t]);
        return;
    }
    idx -= 18432;
    if (idx < 4608)  {
        int ci = idx % 32;
        int t  = (idx / 32) % 9;
        int co = idx / 288;
        ws2[idx] = (co < 9) ? f2bf(s2[((size_t)co * 32 + ci) * 9 + t]) : (ushort_t)0;
        return;
    }
}

// ---------------------------------------------------------------------------
// FUSED enc-conv2 + transformer front (R5 winner: batch-issued loads, 2,256).
// ---------------------------------------------------------------------------
__global__ __launch_bounds__(256, 2) void enc2xf_k(
    const ushort_t* __restrict__ E1b, const ushort_t* __restrict__ Wc2p,
    const float* __restrict__ enc_b2,
    const ushort_t* __restrict__ Wqkv, const float* __restrict__ Bqkv,
    const ushort_t* __restrict__ Wo, const float* __restrict__ Bo,
    const float* __restrict__ g, const float* __restrict__ be,
    ushort_t* __restrict__ T1b)
{
    __shared__ ushort_t Q[128 * 200];   // 51.2 KB
    __shared__ ushort_t WT[9216];       // 18.4 KB: Tl[128*72]

    int tid = threadIdx.x, wave = tid >> 6, lane = tid & 63;
    int lm = lane & 15, quad = lane >> 4;
    int p0 = blockIdx.x * 64;

    // ---- phase 0: enc conv2 (64->64, 3x3), all-taps-hoisted loads ----
    {
        int lr0 = wave * 32;
        int m[2], py[2], px[2];
#pragma unroll
        for (int mt = 0; mt < 2; mt++) {
            int lr = lr0 + mt * 16 + lm;
            int gp = p0 + (lr & 63);
            m[mt] = (lr >> 6) * HW + gp;
            py[mt] = gp / IW;
            px[mt] = gp - py[mt] * IW;
        }

        f32x4 acc[2][4] = {};
        bf16x8 zz = {};
        bf16x8 af[9][2][2];

        // issue ALL 36 input loads back-to-back: ~36 loads in flight.
#pragma unroll
        for (int t = 0; t < 9; t++) {
            int dy = t / 3 - 1, dx = t % 3 - 1;
#pragma unroll
            for (int mt = 0; mt < 2; mt++) {
                bool ok = (unsigned)(py[mt] + dy) < (unsigned)IW &&
                          (unsigned)(px[mt] + dx) < (unsigned)IW;
                const ushort_t* ip = E1b + (size_t)(m[mt] + dy * IW + dx) * 64 + quad * 8;
#pragma unroll
                for (int ks = 0; ks < 2; ks++)
                    af[t][mt][ks] = ok ? ldg8(ip + ks * 32) : zz;
            }
        }

        // weight fragments stream from L2 under the MFMA loop.
#pragma unroll
        for (int t = 0; t < 9; t++) {
#pragma unroll
            for (int nt = 0; nt < 4; nt++)
#pragma unroll
                for (int ks = 0; ks < 2; ks++) {
                    bf16x8 bfv = ldg8(Wc2p + (size_t)(t * 8 + nt * 2 + ks) * 512 + lane * 8);
#pragma unroll
                    for (int mt = 0; mt < 2; mt++)
                        acc[mt][nt] = __builtin_amdgcn_mfma_f32_16x16x32_bf16(
                            af[t][mt][ks], bfv, acc[mt][nt], 0, 0, 0);
                }
        }

#pragma unroll
        for (int nt = 0; nt < 4; nt++) {
            float bv = enc_b2[nt * 16 + lm];
#pragma unroll
            for (int mt = 0; mt < 2; mt++)
#pragma unroll
                for (int r = 0; r < 4; r++) {
                    int lr = lr0 + mt * 16 + quad * 4 + r;
                    WT[lr * 72 + nt * 16 + lm] =
                        f2bf(fmaxf(acc[mt][nt][r] + bv, 0.f));
                }
        }
    }

    // hoist Wqkv fragments (mt-invariant) BEFORE the barrier: the conv
    // epilogue + barrier drain covers their L2 latency.
    bf16x8 wq[12][2];
#pragma unroll
    for (int nt = 0; nt < 12; nt++)
#pragma unroll
        for (int ks = 0; ks < 2; ks++)
            wq[nt][ks] = ldg8(Wqkv + (size_t)(nt * 16 + lm) * 64 + ks * 32 + quad * 8);

    __syncthreads();

    // ---- phase A: qkv projection (input from Tl) into Q ----
#pragma unroll
    for (int mt = 0; mt < 2; mt++) {
        int lA = mt * 64 + wave * 16;
        bf16x8 a[2];
#pragma unroll
        for (int ks = 0; ks < 2; ks++)
            a[ks] = *reinterpret_cast<const bf16x8*>(
                &WT[(lA + lm) * 72 + ks * 32 + quad * 8]);
        f32x4 acc[12] = {};
#pragma unroll
        for (int nt = 0; nt < 12; nt++)
#pragma unroll
            for (int ks = 0; ks < 2; ks++)
                acc[nt] = __builtin_amdgcn_mfma_f32_16x16x32_bf16(
                    a[ks], wq[nt][ks], acc[nt], 0, 0, 0);
        int lrow = lA + quad * 4;
#pragma unroll
        for (int nt = 0; nt < 12; nt++) {
            float bb = Bqkv[nt * 16 + lm];
#pragma unroll
            for (int r = 0; r < 4; r++)
                Q[(lrow + r) * 200 + nt * 16 + lm] = f2bf(acc[nt][r] + bb);
        }
    }
    __syncthreads();

    // ---- phase B: attention (per pixel x head, S=2) ----
    {
        int px = tid >> 2, h = tid & 3;
        ushort_t* r0 = &Q[px * 200 + h * 16];
        ushort_t* r1 = &Q[(64 + px) * 200 + h * 16];

        float q0[16], k0[16], v0[16], q1[16], k1[16], v1[16];
        b2f8(r0,       q0); b2f8(r0 + 8,   q0 + 8);
        b2f8(r0 + 64,  k0); b2f8(r0 + 72,  k0 + 8);
        b2f8(r0 + 128, v0); b2f8(r0 + 136, v0 + 8);
        b2f8(r1,       q1); b2f8(r1 + 8,   q1 + 8);
        b2f8(r1 + 64,  k1); b2f8(r1 + 72,  k1 + 8);
        b2f8(r1 + 128, v1); b2f8(r1 + 136, v1 + 8);

        float s00 = 0, s01 = 0, s10 = 0, s11 = 0;
#pragma unroll
        for (int d = 0; d < 16; d++) {
            s00 += q0[d] * k0[d]; s01 += q0[d] * k1[d];
            s10 += q1[d] * k0[d]; s11 += q1[d] * k1[d];
        }
        s00 *= 0.25f; s01 *= 0.25f; s10 *= 0.25f; s11 *= 0.25f;

        float m0 = fmaxf(s00, s01);
        float e00 = __expf(s00 - m0), e01 = __expf(s01 - m0);
        float i0 = 1.f / (e00 + e01);
        float p00 = e00 * i0, p01 = e01 * i0;

        float m1 = fmaxf(s10, s11);
        float e10 = __expf(s10 - m1), e11 = __expf(s11 - m1);
        float i1 = 1.f / (e10 + e11);
        float p10 = e10 * i1, p11 = e11 * i1;

#pragma unroll
        for (int c = 0; c < 2; c++) {
            ushort8 a0v, a1v;
#pragma unroll
            for (int i = 0; i < 8; i++) {
                int d = c * 8 + i;
                a0v[i] = f2bf(p00 * v0[d] + p01 * v1[d]);
                a1v[i] = f2bf(p10 * v0[d] + p11 * v1[d]);
            }
            *reinterpret_cast<ushort8*>(r0 + c * 8) = a0v;
            *reinterpret_cast<ushort8*>(r1 + c * 8) = a1v;
        }
    }

    // hoist Wo fragments (mt-invariant) before the barrier.
    bf16x8 wo[4][2];
#pragma unroll
    for (int nt = 0; nt < 4; nt++)
#pragma unroll
        for (int ks = 0; ks < 2; ks++)
            wo[nt][ks] = ldg8(Wo + (size_t)(nt * 16 + lm) * 64 + ks * 32 + quad * 8);

    __syncthreads();

    // ---- phase C: out-proj + residual(Tl) + LN1 -> t1 (global) ----
#pragma unroll
    for (int mt = 0; mt < 2; mt++) {
        int lA = mt * 64 + wave * 16;
        size_t gbase = (size_t)((mt == 0 ? p0 : HW + p0) + wave * 16);
        bf16x8 a[2];
#pragma unroll
        for (int ks = 0; ks < 2; ks++)
            a[ks] = *reinterpret_cast<const bf16x8*>(
                &Q[(lA + lm) * 200 + ks * 32 + quad * 8]);
        f32x4 acc[4] = {};
#pragma unroll
        for (int nt = 0; nt < 4; nt++)
#pragma unroll
            for (int ks = 0; ks < 2; ks++)
                acc[nt] = __builtin_amdgcn_mfma_f32_16x16x32_bf16(
                    a[ks], wo[nt][ks], acc[nt], 0, 0, 0);

        float bv[4], gv[4], bev[4];
#pragma unroll
        for (int nt = 0; nt < 4; nt++) {
            bv[nt]  = Bo[nt * 16 + lm];
            gv[nt]  = g[nt * 16 + lm];
            bev[nt] = be[nt * 16 + lm];
        }
#pragma unroll
        for (int r = 0; r < 4; r++) {
            int lr = lA + quad * 4 + r;
            size_t row = gbase + quad * 4 + r;
            float v[4]; float s = 0.f;
#pragma unroll
            for (int nt = 0; nt < 4; nt++) {
                v[nt] = acc[nt][r] + bv[nt] + bf2f(WT[lr * 72 + nt * 16 + lm]);
                s += v[nt];
            }
#pragma unroll
            for (int o = 8; o; o >>= 1) s += __shfl_xor(s, o, 64);
            float mu = s * 0.015625f;
            float q = 0.f;
#pragma unroll
            for (int nt = 0; nt < 4; nt++) { v[nt] -= mu; q += v[nt] * v[nt]; }
#pragma unroll
            for (int o = 8; o; o >>= 1) q += __shfl_xor(q, o, 64);
            float rstd = rsqrtf(q * 0.015625f + 1e-5f);
#pragma unroll
            for (int nt = 0; nt < 4; nt++)
                T1b[row * 64 + nt * 16 + lm] = f2bf(gv[nt] * v[nt] * rstd + bev[nt]);
        }
    }
}

// ---------------------------------------------------------------------------
// sf1 conv (64->32) v2: no LDS, zero barriers, batch-issued loads.
// ---------------------------------------------------------------------------
__global__ __launch_bounds__(256, 2) void neconv2_k(
    const ushort_t* __restrict__ In, const ushort_t* __restrict__ Wp,
    const float* __restrict__ bias, ushort_t* __restrict__ Ob)
{
    int tid = threadIdx.x, wave = tid >> 6, lane = tid & 63;
    int lm = lane & 15, quad = lane >> 4;
    int m0 = blockIdx.x * 128 + wave * 32;

    int m[2], py[2], px[2];
#pragma unroll
    for (int mt = 0; mt < 2; mt++) {
        int mm = m0 + mt * 16 + lm;
        m[mt] = mm;
        int p = mm - (mm >= HW ? HW : 0);
        py[mt] = p / IW;
        px[mt] = p - py[mt] * IW;
    }

    f32x4 acc[2][2] = {};
    bf16x8 zz = {};
    bf16x8 af[9][2][2];

    // issue ALL 36 input loads back-to-back for MLP.
#pragma unroll
    for (int t = 0; t < 9; t++) {
        int dy = t / 3 - 1, dx = t % 3 - 1;
#pragma unroll
        for (int mt = 0; mt < 2; mt++) {
            bool ok = (unsigned)(py[mt] + dy) < (unsigned)IW &&
                      (unsigned)(px[mt] + dx) < (unsigned)IW;
            const ushort_t* ip = In + (size_t)(m[mt] + dy * IW + dx) * 64 + quad * 8;
#pragma unroll
            for (int ks = 0; ks < 2; ks++)
                af[t][mt][ks] = ok ? ldg8(ip + ks * 32) : zz;
        }
    }

    // weight fragments stream from L2 under the MFMA loop.
#pragma unroll
    for (int t = 0; t < 9; t++) {
#pragma unroll
        for (int nt = 0; nt < 2; nt++)
#pragma unroll
            for (int ks = 0; ks < 2; ks++) {
                bf16x8 bfv = ldg8(Wp + (size_t)(t * 4 + nt * 2 + ks) * 512 + lane * 8);
#pragma unroll
                for (int mt = 0; mt < 2; mt++)
                    acc[mt][nt] = __builtin_amdgcn_mfma_f32_16x16x32_bf16(
                        af[t][mt][ks], bfv, acc[mt][nt], 0, 0, 0);
            }
    }

#pragma unroll
    for (int nt = 0; nt < 2; nt++) {
        int col = nt * 16 + lm;
        float bv = bias[col];
#pragma unroll
        for (int mt = 0; mt < 2; mt++)
#pragma unroll
            for (int r = 0; r < 4; r++) {
                int row = m0 + mt * 16 + quad * 4 + r;
                Ob[(size_t)row * 32 + col] = f2bf(acc[mt][nt][r] + bv);
            }
    }
}

// ---------------------------------------------------------------------------
// FFN v9 (measured best: 67-68 us across R1/R6/R7): 3-deep LDS pipeline,
// counted vmcnt, raw s_barrier, B1 staged in LDS, setprio around MFMA.
// FFN is CLOSED: ffn10/ffn12/ffn13 all regressed or neutral.
// ---------------------------------------------------------------------------
__global__ __launch_bounds__(512) void ffn9_k(
    const ushort_t* __restrict__ T1b,
    const ushort_t* __restrict__ W1p, const float* __restrict__ B1,
    const _Float16* __restrict__ W2s, const float* __restrict__ B2,
    const float* __restrict__ g, const float* __restrict__ be,
    ushort_t* __restrict__ OutTb)
{
    __shared__ ushort_t W1lds[3][6144];   // 36 KB
    __shared__ ushort_t W2lds[3][4096];   // 24 KB
    __shared__ float    B1l[2048];        //  8 KB  => 68 KB total

    int tid = threadIdx.x, wave = tid >> 6, lane = tid & 63;
    int lm = lane & 15, quad = lane >> 4;
    int rowbase = blockIdx.x * 256 + wave * 32;

    // stage B1 into LDS (512 threads x float4)
    *reinterpret_cast<float4*>(&B1l[tid * 4]) =
        *reinterpret_cast<const float4*>(B1 + tid * 4);

    bf16x8 Bt[2][2];
#pragma unroll
    for (int mt = 0; mt < 2; mt++)
#pragma unroll
        for (int ks = 0; ks < 2; ks++)
            Bt[mt][ks] = ldg8(T1b + (size_t)(rowbase + mt * 16 + lm) * 64 + ks * 32 + quad * 8);

    // full drain + barrier BEFORE any DMA is issued: B1l visible, vmcnt clean.
    __syncthreads();

    auto dma_chunk = [&](int c, int pb) {
        const ushort_t* g1 = W1p + (size_t)c * 6144;
        const ushort_t* g2 = (const ushort_t*)(W2s + (size_t)c * 4096);
#pragma unroll
        for (int i = 0; i < 3; i++) {
            int idx = i * 8 + wave;
            if (idx < 12)
                dma16(g1 + idx * 512 + lane * 8, &W1lds[pb][idx * 512]);
            else if (idx < 20)
                dma16(g2 + (idx - 12) * 512 + lane * 8,
                      &W2lds[pb][(idx - 12) * 512]);
        }
    };
    // per-wave loads per chunk: waves 0-3 issue 3, waves 4-7 issue 2.

    dma_chunk(0, 0);
    dma_chunk(1, 1);

    f32x4 acc[2][4] = {};

    for (int c = 0; c < 32; c++) {
        int pb = c % 3;

        // counted wait: retire own chunk-c loads, leave chunk-(c+1) in flight.
        if (c < 31) {
            if (wave < 4) asm volatile("s_waitcnt vmcnt(3)" ::: "memory");
            else          asm volatile("s_waitcnt vmcnt(2)" ::: "memory");
        } else {
            asm volatile("s_waitcnt vmcnt(0)" ::: "memory");
        }
        __builtin_amdgcn_s_barrier();
        asm volatile("" ::: "memory");   // fence: no ds_read hoists above barrier

        // depth-2 prefetch: buffer (c+2)%3 == (c-1)%3, fully consumed already.
        if (c + 2 < 32) dma_chunk(c + 2, (c + 2) % 3);

        const ushort_t* w1l = &W1lds[pb][0];
        const ushort_t* w2l = &W2lds[pb][0];

#pragma unroll
        for (int p = 0; p < 2; p++) {
            bf16x8 w1r[2][2];
            f16x8  w2r[4];
            float4 b1r[2];
#pragma unroll
            for (int s = 0; s < 2; s++) {
                int ul = p * 2 + s;
#pragma unroll
                for (int ks = 0; ks < 2; ks++)
                    w1r[s][ks] = *reinterpret_cast<const bf16x8*>(
                        &w1l[(ul * 16 + lm) * 72 + ks * 32 + quad * 8]);
                b1r[s] = *reinterpret_cast<const float4*>(
                    &B1l[(c * 4 + ul) * 16 + quad * 4]);
            }
#pragma unroll
            for (int nt = 0; nt < 4; nt++)
                w2r[nt] = *reinterpret_cast<const f16x8*>(
                    &w2l[((p * 4 + nt) * 64 + lane) * 8]);

            f32x4 h[2][2];
#pragma unroll
            for (int s = 0; s < 2; s++) {
                f32x4 binit = {b1r[s].x, b1r[s].y, b1r[s].z, b1r[s].w};
#pragma unroll
                for (int mt = 0; mt < 2; mt++) h[s][mt] = binit;
            }

            __builtin_amdgcn_s_setprio(1);
#pragma unroll
            for (int s = 0; s < 2; s++)
#pragma unroll
                for (int ks = 0; ks < 2; ks++)
#pragma unroll
                    for (int mt = 0; mt < 2; mt++)
                        h[s][mt] = __builtin_amdgcn_mfma_f32_16x16x32_bf16(
                            w1r[s][ks], Bt[mt][ks], h[s][mt], 0, 0, 0);

            f16x8 aH[2];
#pragma unroll
            for (int mt = 0; mt < 2; mt++) {
                f16x2 t0 = pk16(fmaxf(h[0][mt][0], 0.f), fmaxf(h[0][mt][1], 0.f));
                f16x2 t1 = pk16(fmaxf(h[0][mt][2], 0.f), fmaxf(h[0][mt][3], 0.f));
                f16x2 t2 = pk16(fmaxf(h[1][mt][0], 0.f), fmaxf(h[1][mt][1], 0.f));
                f16x2 t3 = pk16(fmaxf(h[1][mt][2], 0.f), fmaxf(h[1][mt][3], 0.f));
                f16x8 a;
                a[0] = t0[0]; a[1] = t0[1]; a[2] = t1[0]; a[3] = t1[1];
                a[4] = t2[0]; a[5] = t2[1]; a[6] = t3[0]; a[7] = t3[1];
                aH[mt] = a;
            }

#pragma unroll
            for (int nt = 0; nt < 4; nt++)
#pragma unroll
                for (int mt = 0; mt < 2; mt++)
                    acc[mt][nt] = __builtin_amdgcn_mfma_f32_16x16x32_f16(
                        aH[mt], w2r[nt], acc[mt][nt], 0, 0, 0);
            __builtin_amdgcn_s_setprio(0);
        }
    }

    float b2v[4], gv[4], bev[4];
#pragma unroll
    for (int nt = 0; nt < 4; nt++) {
        b2v[nt] = B2[nt * 16 + lm];
        gv[nt]  = g[nt * 16 + lm];
        bev[nt] = be[nt * 16 + lm];
    }
#pragma unroll
    for (int mt = 0; mt < 2; mt++)
#pragma unroll
        for (int r = 0; r < 4; r++) {
            int row = rowbase + mt * 16 + quad * 4 + r;
            float v[4]; float s = 0.f;
#pragma unroll
            for (int nt = 0; nt < 4; nt++) {
                v[nt] = acc[mt][nt][r] + b2v[nt] +
                        bf2f(T1b[(size_t)row * 64 + nt * 16 + lm]);
                s += v[nt];
            }
#pragma unroll
            for (int o = 8; o; o >>= 1) s += __shfl_xor(s, o, 64);
            float mu = s * 0.015625f;
            float q = 0.f;
#pragma unroll
            for (int nt = 0; nt < 4; nt++) { v[nt] -= mu; q += v[nt] * v[nt]; }
#pragma unroll
            for (int o = 8; o; o >>= 1) q += __shfl_xor(q, o, 64);
            float rstd = rsqrtf(q * 0.015625f + 1e-5f);
#pragma unroll
            for (int nt = 0; nt < 4; nt++)
                OutTb[(size_t)row * 64 + nt * 16 + lm] =
                    f2bf(gv[nt] * v[nt] * rstd + bev[nt]);
        }
}

// ---------------------------------------------------------------------------
// sf2 conv (32->9, MFMA) fused with KPN dynamic filtering (R6 batch-issue).
// ---------------------------------------------------------------------------
__global__ __launch_bounds__(256) void sf2kpn_k(
    const ushort_t* __restrict__ In,
    const ushort_t* __restrict__ Wsw,
    const float* __restrict__ bias,
    const float* __restrict__ x,
    float* __restrict__ fused)
{
    __shared__ float Fl[128 * 12];
    int tid = threadIdx.x, wave = tid >> 6, lane = tid & 63;
    int lm = lane & 15, quad = lane >> 4;
    int m0 = blockIdx.x * 128 + wave * 32;

    int m[2], py[2], px[2];
#pragma unroll
    for (int mt = 0; mt < 2; mt++) {
        int mm = m0 + mt * 16 + lm;
        m[mt] = mm;
        int p = mm - (mm >= HW ? HW : 0);
        py[mt] = p / IW;
        px[mt] = p - py[mt] * IW;
    }

    f32x4 acc[2] = {};
    bf16x8 zz = {};
    bf16x8 af[9][2];
    bf16x8 wv[9];

    // batch-issue all input + weight loads for MLP.
#pragma unroll
    for (int t = 0; t < 9; t++) {
        int dy = t / 3 - 1, dx = t % 3 - 1;
#pragma unroll
        for (int mt = 0; mt < 2; mt++) {
            bool ok = (unsigned)(py[mt] + dy) < (unsigned)IW &&
                      (unsigned)(px[mt] + dx) < (unsigned)IW;
            af[t][mt] = ok ? ldg8(In + (size_t)(m[mt] + dy * IW + dx) * 32 + quad * 8) : zz;
        }
    }
#pragma unroll
    for (int t = 0; t < 9; t++)
        wv[t] = ldg8(Wsw + ((size_t)lm * 9 + t) * 32 + quad * 8);

#pragma unroll
    for (int t = 0; t < 9; t++)
#pragma unroll
        for (int mt = 0; mt < 2; mt++)
            acc[mt] = __builtin_amdgcn_mfma_f32_16x16x32_bf16(af[t][mt], wv[t], acc[mt], 0, 0, 0);

    if (lm < 9) {
        float bv = bias[lm];
#pragma unroll
        for (int mt = 0; mt < 2; mt++)
#pragma unroll
            for (int r = 0; r < 4; r++) {
                int lrow = wave * 32 + mt * 16 + quad * 4 + r;
                Fl[lrow * 12 + lm] = acc[mt][r] + bv;
            }
    }
    __syncthreads();

    if (tid < 128) {
        int gid = blockIdx.x * 128 + tid;
        int b = gid >= HW;
        int p = gid - b * HW;
        int y = p / IW, xx = p - y * IW;
        const float* fp = &Fl[tid * 12];
        const float* xp = x + (size_t)b * 3 * HW;
        float a = 0.f;
#pragma unroll
        for (int u = 0; u < 3; u++) {
            int yy = y + u - 1;
            if ((unsigned)yy >= (unsigned)IW) continue;
#pragma unroll
            for (int v = 0; v < 3; v++) {
                int xc = xx + v - 1;
                if ((unsigned)xc >= (unsigned)IW) continue;
                int o = yy * IW + xc;
                float s = xp[o] + xp[HW + o] + xp[2 * HW + o];
                a += fp[u * 3 + v] * s;
            }
        }
        fused[gid] = a;
    }
}

// ---------------------------------------------------------------------------
// Halo-fused decoder: 16x16 pixel tile/block. Stages the 20x20 fused patch
// in LDS, computes the 18x18 f16 hidden field in LDS (stride 72 halves to
// break the 128B-stride bank conflict), then conv2+sigmoid from LDS.
// Removes the 12.8MB Hb global round-trip and one kernel launch. Numerics
// identical to the dec1/dec2 split (same f16 rounding, same n-outer order,
// same edge masking).
// ---------------------------------------------------------------------------
__global__ __launch_bounds__(256) void dec_tile_k(
    const float* __restrict__ fused,
    const float* __restrict__ w1, const float* __restrict__ b1,
    const float* __restrict__ w2, const float* __restrict__ b2,
    float* __restrict__ out)
{
    __shared__ float    Fs[400];          // 20x20 fused patch (halo 2)
    __shared__ _Float16 Hl[324 * 72];     // 18x18 x 64ch hidden, stride 72

    int tid = threadIdx.x;
    int b   = blockIdx.x / 196;
    int rem = blockIdx.x - b * 196;
    int ty0 = (rem / 14) * 16;
    int tx0 = (rem % 14) * 16;
    const float* fp = fused + (size_t)b * HW;

    // ---- stage fused 20x20 patch (zero-padded at image edges) ----
    for (int k = tid; k < 400; k += 256) {
        int fy = k / 20, fx = k - fy * 20;
        int gy = ty0 + fy - 2, gx = tx0 + fx - 2;
        float t = 0.f;
        if ((unsigned)gy < (unsigned)IW && (unsigned)gx < (unsigned)IW)
            t = fp[gy * IW + gx];
        Fs[k] = t;
    }
    __syncthreads();

    // ---- hidden field on 18x18 (halo 1), f16, zeroed off-image ----
    for (int ph = tid; ph < 324; ph += 256) {
        int hy = ph / 18, hx = ph - hy * 18;
        int gy = ty0 + hy - 1, gx = tx0 + hx - 1;
        _Float16* op = &Hl[ph * 72];
        if ((unsigned)gy >= (unsigned)IW || (unsigned)gx >= (unsigned)IW) {
            f16x8 z = {};
#pragma unroll
            for (int g = 0; g < 8; g++)
                *reinterpret_cast<f16x8*>(op + g * 8) = z;
        } else {
            float F[9];
#pragma unroll
            for (int s = 0; s < 9; s++)
                F[s] = Fs[(hy + s / 3) * 20 + (hx + s % 3)];
#pragma unroll
            for (int g = 0; g < 8; g++) {
                f16x8 o;
#pragma unroll
                for (int i = 0; i < 8; i++) {
                    int c = g * 8 + i;
                    float h = b1[c];
                    const float* wp = w1 + c * 9;
#pragma unroll
                    for (int s = 0; s < 9; s++) h = fmaf(F[s], wp[s], h);
                    o[i] = (_Float16)fmaxf(h, 0.f);
                }
                *reinterpret_cast<f16x8*>(op + g * 8) = o;
            }
        }
    }
    __syncthreads();

    // ---- conv2 (64->1) + sigmoid from LDS hidden ----
    {
        int ty = tid >> 4, tx = tid & 15;
        int gy = ty0 + ty, gx = tx0 + tx;
        float acc = b2[0];
#pragma unroll
        for (int n = 0; n < 9; n++) {
            int dy = n / 3 - 1, dx = n % 3 - 1;
            int yy = gy + dy, xc = gx + dx;
            if ((unsigned)yy >= (unsigned)IW || (unsigned)xc >= (unsigned)IW) continue;
            const _Float16* hp = &Hl[((ty + 1 + dy) * 18 + (tx + 1 + dx)) * 72];
#pragma unroll
            for (int g = 0; g < 8; g++) {
                f16x8 hv = *reinterpret_cast<const f16x8*>(hp + g * 8);
#pragma unroll
                for (int i = 0; i < 8; i++)
                    acc = fmaf((float)hv[i], w2[(g * 8 + i) * 9 + n], acc);
            }
        }
        out[(size_t)b * HW + gy * IW + gx] = 1.f / (1.f + __expf(-acc));
    }
}

// ---------------------------------------------------------------------------
extern "C" void kernel_launch(void* const* d_in, const int* in_sizes, int n_in,
                              void* d_out, int out_size, void* d_ws, size_t ws_size,
                              hipStream_t stream)
{
    const float* x      = (const float*)d_in[0];
    const float* enc_w1 = (const float*)d_in[1];
    const float* enc_b1 = (const float*)d_in[2];
    const float* enc_w2 = (const float*)d_in[3];
    const float* enc_b2 = (const float*)d_in[4];
    const float* in_w   = (const float*)d_in[5];
    const float* in_b   = (const float*)d_in[6];
    const float* out_w  = (const float*)d_in[7];
    const float* out_b  = (const float*)d_in[8];
    const float* ln1_g  = (const float*)d_in[9];
    const float* ln1_b  = (const float*)d_in[10];
    const float* ffn_w1 = (const float*)d_in[11];
    const float* ffn_b1 = (const float*)d_in[12];
    const float* ffn_w2 = (const float*)d_in[13];
    const float* ffn_b2 = (const float*)d_in[14];
    const float* ln2_g  = (const float*)d_in[15];
    const float* ln2_b  = (const float*)d_in[16];
    const float* sf_w1  = (const float*)d_in[17];
    const float* sf_b1  = (const float*)d_in[18];
    const float* sf_w2  = (const float*)d_in[19];
    const float* sf_b2  = (const float*)d_in[20];
    const float* dec_w1 = (const float*)d_in[21];
    const float* dec_b1 = (const float*)d_in[22];
    const float* dec_w2 = (const float*)d_in[23];
    const float* dec_b2 = (const float*)d_in[24];

    float* ws = (float*)d_ws;
    const size_t SZ = (size_t)NPIX * 64;

    ushort_t* E1b  = (ushort_t*)(ws + 5 * SZ);             // conv1 out / t2 bf16
    ushort_t* Tb   = (ushort_t*)(ws + 11 * SZ / 2);        // t1 bf16
    ushort_t* wu   = (ushort_t*)(ws + 6 * SZ);             // weights
    ushort_t* in_wb  = wu;                                 // 12288
    ushort_t* out_wb = wu + 12288;                         // 4096
    ushort_t* w1p    = wu + 16384;                         // 196608 (padded chunks)
    _Float16* w2s    = (_Float16*)(wu + 212992);           // 131072 halves
    ushort_t* wc2p   = wu + 344064;                        // 36864 (coalesced frags)
    ushort_t* ws1p   = wu + 385536;                        // 18432 (coalesced frags)
    ushort_t* ws2    = wu + 408576;                        // 4608
    // late-stage scratch:
    float*    base3 = ws + 3 * SZ;
    ushort_t* s1b   = (ushort_t*)base3;                    // NPIX*32 bf16
    float*    fused = base3 + SZ / 2;                      // NPIX

    // ---- merged weight prep + conv1 ----
    prep_conv1_k<<<1714, 256, 0, stream>>>(
        x, enc_w1, enc_b1, E1b,
        in_w, in_wb, out_w, out_wb, ffn_w1, w1p,
        ffn_w2, w2s, enc_w2, wc2p, sf_w1, ws1p, sf_w2, ws2);

    // ---- fused enc-conv2 + transformer front -> t1 (Tb) ----
    enc2xf_k<<<784, 256, 0, stream>>>(E1b, wc2p, enc_b2,
                                      in_wb, in_b, out_wb, out_b,
                                      ln1_g, ln1_b, Tb);
    // ---- FFN (+res+LN2) -> t2 (E1b, dead after enc2xf) ----
    ffn9_k<<<392, 512, 0, stream>>>(Tb, w1p, ffn_b1, w2s, ffn_b2, ln2_g, ln2_b, E1b);
    // ---- filter prediction (sf1, barrier-free v2) ----
    neconv2_k<<<784, 256, 0, stream>>>(E1b, ws1p, sf_b1, s1b);
    // ---- sf2 conv + KPN fused ----
    sf2kpn_k<<<784, 256, 0, stream>>>(s1b, ws2, sf_b2, x, fused);
    // ---- halo-fused decoder (replaces dec1+dec2, no Hb round-trip) ----
    dec_tile_k<<<392, 256, 0, stream>>>(fused, dec_w1, dec_b1, dec_w2, dec_b2,
                                        (float*)d_out);
}